// Round 2
// baseline (382.004 us; speedup 1.0000x reference)
//
#include <hip/hip_runtime.h>
#include <hip/hip_bf16.h>

#define NN 50000
#define EE 800000

typedef __bf16 bf16x8 __attribute__((ext_vector_type(8)));
typedef float f32x4 __attribute__((ext_vector_type(4)));

__device__ inline float bf2f(unsigned short u) {
    union { unsigned int i; float f; } x; x.i = ((unsigned int)u) << 16; return x.f;
}
__device__ inline unsigned int packbf2(float lo, float hi) {
    __bf16 a = (__bf16)lo, b = (__bf16)hi;
    unsigned short ua = *(unsigned short*)&a, ub = *(unsigned short*)&b;
    return (unsigned int)ua | ((unsigned int)ub << 16);
}

// ---------------- zero deg/cursor (NO hipMemsetAsync — graph-safe) ----------------
__global__ void k_zero(int* __restrict__ deg, int* __restrict__ curs) {
    int i = blockIdx.x * 256 + threadIdx.x;
    if (i < NN) { deg[i] = 0; curs[i] = 0; }
}

// ---------------- CSR build ----------------
__global__ void k_deg(const int* __restrict__ et, int* __restrict__ deg) {
    int e = blockIdx.x * 256 + threadIdx.x;
    if (e < EE) atomicAdd(&deg[et[e * 3 + 2]], 1);
}

__global__ void k_scan1(const int* __restrict__ deg, int* __restrict__ incl, int* __restrict__ bsum) {
    __shared__ int s[1024];
    int i = blockIdx.x * 1024 + threadIdx.x;
    int v = (i < NN) ? deg[i] : 0;
    s[threadIdx.x] = v;
    __syncthreads();
    for (int off = 1; off < 1024; off <<= 1) {
        int t = (threadIdx.x >= off) ? s[threadIdx.x - off] : 0;
        __syncthreads();
        s[threadIdx.x] += t;
        __syncthreads();
    }
    if (i < NN) incl[i] = s[threadIdx.x];
    if (threadIdx.x == 1023) bsum[blockIdx.x] = s[1023];
}

__global__ void k_scan2(const int* __restrict__ bsum, int* __restrict__ boff) {
    if (threadIdx.x == 0 && blockIdx.x == 0) {
        int acc = 0;
        for (int i = 0; i < 49; ++i) { boff[i] = acc; acc += bsum[i]; }
    }
}

__global__ void k_scan3(const int* __restrict__ incl, const int* __restrict__ deg,
                        const int* __restrict__ boff, int* __restrict__ row_start) {
    int i = blockIdx.x * 1024 + threadIdx.x;
    if (i < NN) row_start[i] = incl[i] - deg[i] + boff[blockIdx.x];
}

__global__ void k_fill(const int* __restrict__ et, const int* __restrict__ row_start,
                       int* __restrict__ cursor, int* __restrict__ perm) {
    int e = blockIdx.x * 256 + threadIdx.x;
    if (e >= EE) return;
    int src = et[e * 3 + 0];
    int rel = et[e * 3 + 1];
    int dst = et[e * 3 + 2];
    int pos = row_start[dst] + atomicAdd(&cursor[dst], 1);
    perm[pos] = src | (rel << 16);      // src < 65536, rel < 16
}

// ---------------- weight prep ----------------
// input GEMM: Wt[o*128 + k] = input_w[k*128 + o]
__global__ void k_prep_wt_in(const float* __restrict__ W, __bf16* __restrict__ Wt) {
    int i = blockIdx.x * 256 + threadIdx.x;   // 16384
    int o = i >> 7, k = i & 127;
    Wt[(size_t)o * 128 + k] = (__bf16)W[(size_t)k * 128 + o];
}

// layer GEMM: Wt[o*640 + k]; k<512: basis[b=k>>7][k&127][o]; k>=512: root_w[k-512][o]
__global__ void k_prep_wt_layer(const float* __restrict__ basis, const float* __restrict__ rootw,
                                __bf16* __restrict__ Wt) {
    int i = blockIdx.x * 256 + threadIdx.x;   // 640*128 = 81920
    int o = i >> 9, k = i & 511;              // careful: need o in 0..127, k in 0..639
    // remap: i = o*640 + k won't tile evenly by 512; do direct:
    int idx = blockIdx.x * 256 + threadIdx.x;
    if (idx >= 128 * 640) return;
    o = idx / 640; k = idx - o * 640;
    float v;
    if (k < 512) v = basis[(size_t)(k >> 7) * 16384 + (size_t)(k & 127) * 128 + o];
    else         v = rootw[(size_t)(k - 512) * 128 + o];
    Wt[(size_t)o * 640 + k] = (__bf16)v;
}

// ---------------- input GEMM: x0 = nf(f32) @ input_w + b  (bf16 out) ----------------
__global__ void k_gemm_in(const float* __restrict__ A, const __bf16* __restrict__ Wt,
                          const float* __restrict__ bias, __bf16* __restrict__ out, int M) {
    const int tid = threadIdx.x, wave = tid >> 6, lane = tid & 63;
    const int wr = wave >> 1, wc = wave & 1;
    const int r0 = blockIdx.x * 128 + wr * 64;
    const int c0 = wc * 64;
    const int l15 = lane & 15, lhi = lane >> 4;
    f32x4 acc[4][4] = {};
    #pragma unroll
    for (int kk = 0; kk < 4; ++kk) {
        const int kb = kk * 32 + lhi * 8;
        bf16x8 a[4], b[4];
        #pragma unroll
        for (int m = 0; m < 4; ++m) {
            int row = r0 + m * 16 + l15;
            row = row < M ? row : M - 1;
            const float* ap = A + (size_t)row * 128 + kb;
            float4 v0 = *(const float4*)ap;
            float4 v1 = *(const float4*)(ap + 4);
            bf16x8 f;
            f[0]=(__bf16)v0.x; f[1]=(__bf16)v0.y; f[2]=(__bf16)v0.z; f[3]=(__bf16)v0.w;
            f[4]=(__bf16)v1.x; f[5]=(__bf16)v1.y; f[6]=(__bf16)v1.z; f[7]=(__bf16)v1.w;
            a[m] = f;
        }
        #pragma unroll
        for (int n = 0; n < 4; ++n) {
            int col = c0 + n * 16 + l15;
            b[n] = *(const bf16x8*)(Wt + (size_t)col * 128 + kb);
        }
        #pragma unroll
        for (int m = 0; m < 4; ++m)
            #pragma unroll
            for (int n = 0; n < 4; ++n)
                acc[m][n] = __builtin_amdgcn_mfma_f32_16x16x32_bf16(a[m], b[n], acc[m][n], 0, 0, 0);
    }
    #pragma unroll
    for (int m = 0; m < 4; ++m)
        #pragma unroll
        for (int j = 0; j < 4; ++j) {
            int row = r0 + m * 16 + lhi * 4 + j;
            if (row >= M) continue;
            #pragma unroll
            for (int n = 0; n < 4; ++n) {
                int col = c0 + n * 16 + l15;
                out[(size_t)row * 128 + col] = (__bf16)(acc[m][n][j] + bias[col]);
            }
        }
}

// ---------------- gather + per-basis aggregate (chunk of dst nodes) ----------------
// one wave per dst node; lane owns channels 2*lane, 2*lane+1
__global__ void k_agg2(const __bf16* __restrict__ x, const int* __restrict__ perm,
                       const int* __restrict__ rowst, const int* __restrict__ deg,
                       const float* __restrict__ att, __bf16* __restrict__ agg,
                       int nodeOff, int nodeCnt) {
    int local = blockIdx.x * 4 + (threadIdx.x >> 6);
    if (local >= nodeCnt) return;
    int node = nodeOff + local;
    int lane = threadIdx.x & 63;
    int start = rowst[node], cnt = deg[node];
    const unsigned int* xs = (const unsigned int*)x;   // 2 bf16 per u32, row stride 64 u32
    float a0=0,a1=0,a2=0,a3=0,a4=0,a5=0,a6=0,a7=0;
    for (int i = 0; i < cnt; ++i) {
        int p = perm[start + i];
        int srcn = p & 0xFFFF;
        int r    = p >> 16;
        float4 cf = *(const float4*)(att + r * 4);
        unsigned int u = xs[(size_t)srcn * 64 + lane];
        float xlo = bf2f((unsigned short)(u & 0xFFFF));
        float xhi = bf2f((unsigned short)(u >> 16));
        a0 += cf.x * xlo; a1 += cf.x * xhi;
        a2 += cf.y * xlo; a3 += cf.y * xhi;
        a4 += cf.z * xlo; a5 += cf.z * xhi;
        a6 += cf.w * xlo; a7 += cf.w * xhi;
    }
    float dinv = (cnt > 0) ? 1.f / (float)cnt : 0.f;
    unsigned int* ao = (unsigned int*)(agg + (size_t)local * 512);
    ao[0 * 64 + lane] = packbf2(a0 * dinv, a1 * dinv);
    ao[1 * 64 + lane] = packbf2(a2 * dinv, a3 * dinv);
    ao[2 * 64 + lane] = packbf2(a4 * dinv, a5 * dinv);
    ao[3 * 64 + lane] = packbf2(a6 * dinv, a7 * dinv);
}

// ---------------- layer GEMM: y = [agg | x] @ Wt(128x640)^T + rb ; LN(+ReLU) fused ----------------
// OUTF=0: ReLU + bf16 out ; OUTF=1: f32 out (final)
template<int OUTF>
__global__ void k_gemm_layer(const __bf16* __restrict__ agg, const __bf16* __restrict__ x,
                             const __bf16* __restrict__ Wt, const float* __restrict__ rb,
                             const float* __restrict__ g, const float* __restrict__ bb,
                             __bf16* __restrict__ outB, float* __restrict__ outF,
                             int rowOff, int nodeCnt) {
    __shared__ float red[2][2][128];   // [sum|sq][wc][row-in-block]
    __shared__ float murs[2][128];     // [mu|rstd][row-in-block]
    const int tid = threadIdx.x, wave = tid >> 6, lane = tid & 63;
    const int wr = wave >> 1, wc = wave & 1;
    const int lr0 = blockIdx.x * 128 + wr * 64;   // chunk-local row base for A loads
    const int c0 = wc * 64;
    const int l15 = lane & 15, lhi = lane >> 4;
    f32x4 acc[4][4] = {};
    #pragma unroll
    for (int kk = 0; kk < 20; ++kk) {
        const int kb = kk * 32 + lhi * 8;
        bf16x8 a[4], b[4];
        #pragma unroll
        for (int m = 0; m < 4; ++m) {
            int lr = lr0 + m * 16 + l15;
            lr = lr < nodeCnt ? lr : nodeCnt - 1;
            if (kk < 16) a[m] = *(const bf16x8*)(agg + (size_t)lr * 512 + kb);
            else         a[m] = *(const bf16x8*)(x + (size_t)(rowOff + lr) * 128 + (kb - 512));
        }
        #pragma unroll
        for (int n = 0; n < 4; ++n) {
            int col = c0 + n * 16 + l15;
            b[n] = *(const bf16x8*)(Wt + (size_t)col * 640 + kb);
        }
        #pragma unroll
        for (int m = 0; m < 4; ++m)
            #pragma unroll
            for (int n = 0; n < 4; ++n)
                acc[m][n] = __builtin_amdgcn_mfma_f32_16x16x32_bf16(a[m], b[n], acc[m][n], 0, 0, 0);
    }
    // + root bias, then per-row sum/sumsq partials (16-lane butterfly within lhi group)
    float colb[4];
    #pragma unroll
    for (int n = 0; n < 4; ++n) colb[n] = rb[c0 + n * 16 + l15];
    #pragma unroll
    for (int m = 0; m < 4; ++m)
        #pragma unroll
        for (int j = 0; j < 4; ++j) {
            float s = 0.f, q = 0.f;
            #pragma unroll
            for (int n = 0; n < 4; ++n) {
                float v = acc[m][n][j] + colb[n];
                acc[m][n][j] = v;
                s += v; q += v * v;
            }
            #pragma unroll
            for (int o = 1; o < 16; o <<= 1) { s += __shfl_xor(s, o); q += __shfl_xor(q, o); }
            if (l15 == 0) {
                int r = wr * 64 + m * 16 + lhi * 4 + j;
                red[0][wc][r] = s; red[1][wc][r] = q;
            }
        }
    __syncthreads();
    if (tid < 128) {
        float s = red[0][0][tid] + red[0][1][tid];
        float q = red[1][0][tid] + red[1][1][tid];
        float mu = s * (1.f / 128.f);
        float var = q * (1.f / 128.f) - mu * mu;
        murs[0][tid] = mu;
        murs[1][tid] = rsqrtf(var + 1e-5f);
    }
    __syncthreads();
    float gg[4], gb[4];
    #pragma unroll
    for (int n = 0; n < 4; ++n) {
        int col = c0 + n * 16 + l15;
        gg[n] = g[col]; gb[n] = bb[col];
    }
    #pragma unroll
    for (int m = 0; m < 4; ++m)
        #pragma unroll
        for (int j = 0; j < 4; ++j) {
            int rblk = wr * 64 + m * 16 + lhi * 4 + j;
            int lr = blockIdx.x * 128 + rblk;
            if (lr >= nodeCnt) continue;
            float mu = murs[0][rblk], rs = murs[1][rblk];
            size_t rowbase = (size_t)(rowOff + lr) * 128;
            #pragma unroll
            for (int n = 0; n < 4; ++n) {
                int col = c0 + n * 16 + l15;
                float v = (acc[m][n][j] - mu) * rs * gg[n] + gb[n];
                if (OUTF == 0) { v = fmaxf(v, 0.f); outB[rowbase + col] = (__bf16)v; }
                else           { outF[rowbase + col] = v; }
            }
        }
}

// ---------------- launch ----------------
extern "C" void kernel_launch(void* const* d_in, const int* in_sizes, int n_in,
                              void* d_out, int out_size, void* d_ws, size_t ws_size,
                              hipStream_t stream) {
    const float* nf      = (const float*)d_in[0];
    const int*   et      = (const int*)d_in[1];
    const float* input_w = (const float*)d_in[3];
    const float* input_b = (const float*)d_in[4];
    const float* basis0  = (const float*)d_in[5];
    const float* att0    = (const float*)d_in[6];
    const float* rootw0  = (const float*)d_in[7];
    const float* rootb0  = (const float*)d_in[8];
    const float* lng0    = (const float*)d_in[9];
    const float* lnb0    = (const float*)d_in[10];
    const float* basis1  = (const float*)d_in[11];
    const float* att1    = (const float*)d_in[12];
    const float* rootw1  = (const float*)d_in[13];
    const float* rootb1  = (const float*)d_in[14];
    const float* lng1    = (const float*)d_in[15];
    const float* lnb1    = (const float*)d_in[16];
    (void)in_sizes; (void)n_in; (void)out_size;

    char* ws = (char*)d_ws;
    size_t off = 0;
    auto carve = [&](size_t bytes) { char* p = ws + off; off = (off + bytes + 255) & ~(size_t)255; return p; };
    __bf16* x0    = (__bf16*)carve((size_t)NN * 128 * 2);     // 12.8 MB
    __bf16* x1    = (__bf16*)carve((size_t)NN * 128 * 2);     // 12.8 MB
    __bf16* Wt    = (__bf16*)carve((size_t)128 * 640 * 2);    // 160 KB
    int*    deg   = (int*)carve((size_t)NN * 4);
    int*    incl  = (int*)carve((size_t)NN * 4);
    int*    rowst = (int*)carve((size_t)NN * 4);
    int*    curs  = (int*)carve((size_t)NN * 4);
    int*    bsum  = (int*)carve(64 * 4);
    int*    boff  = (int*)carve(64 * 4);
    int*    perm  = (int*)carve((size_t)EE * 4);              // 3.2 MB
    // agg gets whatever remains; chunk the per-node aggregation to fit ws_size.
    size_t remain = (ws_size > off + 4096) ? (ws_size - off - 4096) : 0;
    long long maxNodes = (long long)(remain / 1024);          // 512 bf16 = 1 KB per node
    int chunkN = (maxNodes >= NN) ? NN : (int)maxNodes;
    if (chunkN < 512) chunkN = 512;                           // last-resort floor
    __bf16* agg = (__bf16*)carve((size_t)chunkN * 512 * 2);
    int nch = (NN + chunkN - 1) / chunkN;

    // CSR build
    k_zero<<<(NN + 255) / 256, 256, 0, stream>>>(deg, curs);
    k_deg<<<(EE + 255) / 256, 256, 0, stream>>>(et, deg);
    k_scan1<<<49, 1024, 0, stream>>>(deg, incl, bsum);
    k_scan2<<<1, 64, 0, stream>>>(bsum, boff);
    k_scan3<<<49, 1024, 0, stream>>>(incl, deg, boff, rowst);
    k_fill<<<(EE + 255) / 256, 256, 0, stream>>>(et, rowst, curs, perm);

    // input projection
    k_prep_wt_in<<<64, 256, 0, stream>>>(input_w, Wt);
    k_gemm_in<<<(NN + 127) / 128, 256, 0, stream>>>(nf, Wt, input_b, x0, NN);

    // layer 0
    k_prep_wt_layer<<<(128 * 640 + 255) / 256, 256, 0, stream>>>(basis0, rootw0, Wt);
    for (int c = 0; c < nch; ++c) {
        int o0 = c * chunkN;
        int cnt = (o0 + chunkN <= NN) ? chunkN : (NN - o0);
        k_agg2<<<(cnt + 3) / 4, 256, 0, stream>>>(x0, perm, rowst, deg, att0, agg, o0, cnt);
        k_gemm_layer<0><<<(cnt + 127) / 128, 256, 0, stream>>>(agg, x0, Wt, rootb0, lng0, lnb0,
                                                               x1, nullptr, o0, cnt);
    }

    // layer 1
    k_prep_wt_layer<<<(128 * 640 + 255) / 256, 256, 0, stream>>>(basis1, rootw1, Wt);
    for (int c = 0; c < nch; ++c) {
        int o0 = c * chunkN;
        int cnt = (o0 + chunkN <= NN) ? chunkN : (NN - o0);
        k_agg2<<<(cnt + 3) / 4, 256, 0, stream>>>(x1, perm, rowst, deg, att1, agg, o0, cnt);
        k_gemm_layer<1><<<(cnt + 127) / 128, 256, 0, stream>>>(agg, x1, Wt, rootb1, lng1, lnb1,
                                                               nullptr, (float*)d_out, o0, cnt);
    }
}

// Round 3
// 284.021 us; speedup vs baseline: 1.3450x; 1.3450x over previous
//
#include <hip/hip_runtime.h>
#include <hip/hip_bf16.h>

#define NN 50000
#define EE 800000

typedef __bf16 bf16x8 __attribute__((ext_vector_type(8)));
typedef float f32x4 __attribute__((ext_vector_type(4)));

__device__ inline float bf2f(unsigned int u) {
    union { unsigned int i; float f; } x; x.i = (u & 0xFFFFu) << 16; return x.f;
}
__device__ inline float bf2fh(unsigned int u) {
    union { unsigned int i; float f; } x; x.i = u & 0xFFFF0000u; return x.f;
}
__device__ inline unsigned int packbf2(float lo, float hi) {
    __bf16 a = (__bf16)lo, b = (__bf16)hi;
    unsigned short ua = *(unsigned short*)&a, ub = *(unsigned short*)&b;
    return (unsigned int)ua | ((unsigned int)ub << 16);
}

// ---------------- zero deg/cursor (graph-safe, no hipMemsetAsync) ----------------
__global__ void k_zero(int* __restrict__ deg, int* __restrict__ curs) {
    int i = blockIdx.x * 256 + threadIdx.x;
    if (i < NN) { deg[i] = 0; curs[i] = 0; }
}

// ---------------- CSR build ----------------
__global__ void k_deg(const int* __restrict__ et, int* __restrict__ deg) {
    int e = blockIdx.x * 256 + threadIdx.x;
    if (e < EE) atomicAdd(&deg[et[e * 3 + 2]], 1);
}

__global__ void k_scan1(const int* __restrict__ deg, int* __restrict__ incl, int* __restrict__ bsum) {
    __shared__ int s[1024];
    int i = blockIdx.x * 1024 + threadIdx.x;
    int v = (i < NN) ? deg[i] : 0;
    s[threadIdx.x] = v;
    __syncthreads();
    for (int off = 1; off < 1024; off <<= 1) {
        int t = (threadIdx.x >= off) ? s[threadIdx.x - off] : 0;
        __syncthreads();
        s[threadIdx.x] += t;
        __syncthreads();
    }
    if (i < NN) incl[i] = s[threadIdx.x];
    if (threadIdx.x == 1023) bsum[blockIdx.x] = s[1023];
}

__global__ void k_scan2(const int* __restrict__ bsum, int* __restrict__ boff) {
    if (threadIdx.x == 0 && blockIdx.x == 0) {
        int acc = 0;
        for (int i = 0; i < 49; ++i) { boff[i] = acc; acc += bsum[i]; }
    }
}

__global__ void k_scan3(const int* __restrict__ incl, const int* __restrict__ deg,
                        const int* __restrict__ boff, int* __restrict__ row_start) {
    int i = blockIdx.x * 1024 + threadIdx.x;
    if (i < NN) row_start[i] = incl[i] - deg[i] + boff[blockIdx.x];
}

__global__ void k_fill(const int* __restrict__ et, const int* __restrict__ row_start,
                       int* __restrict__ cursor, int* __restrict__ perm) {
    int e = blockIdx.x * 256 + threadIdx.x;
    if (e >= EE) return;
    int src = et[e * 3 + 0];
    int rel = et[e * 3 + 1];
    int dst = et[e * 3 + 2];
    int pos = row_start[dst] + atomicAdd(&cursor[dst], 1);
    perm[pos] = src | (rel << 16);      // src < 65536, rel < 16
}

// ---------------- unified weight prep (one dispatch) ----------------
// WtIn[o*128+k] = input_w[k][o]
// Wt{0,1}[o*640+k]: k<512 -> basis[k>>7][k&127][o]; k>=512 -> root_w[k-512][o]
__global__ void k_prep(const float* __restrict__ iw,
                       const float* __restrict__ basis0, const float* __restrict__ rootw0,
                       const float* __restrict__ basis1, const float* __restrict__ rootw1,
                       __bf16* __restrict__ WtIn, __bf16* __restrict__ Wt0, __bf16* __restrict__ Wt1) {
    int idx = blockIdx.x * 256 + threadIdx.x;
    if (idx < 16384) {
        int o = idx >> 7, k = idx & 127;
        WtIn[(size_t)o * 128 + k] = (__bf16)iw[(size_t)k * 128 + o];
        return;
    }
    idx -= 16384;
    const float* basis = basis0; const float* rootw = rootw0; __bf16* Wt = Wt0;
    if (idx >= 81920) { idx -= 81920; basis = basis1; rootw = rootw1; Wt = Wt1; }
    if (idx >= 81920) return;
    int o = idx / 640, k = idx - o * 640;
    float v;
    if (k < 512) v = basis[(size_t)(k >> 7) * 16384 + (size_t)(k & 127) * 128 + o];
    else         v = rootw[(size_t)(k - 512) * 128 + o];
    Wt[(size_t)o * 640 + k] = (__bf16)v;
}

// ---------------- input GEMM: x0 = nf(f32) @ input_w + b  (bf16 out) ----------------
__global__ void k_gemm_in(const float* __restrict__ A, const __bf16* __restrict__ Wt,
                          const float* __restrict__ bias, __bf16* __restrict__ out, int M) {
    const int tid = threadIdx.x, wave = tid >> 6, lane = tid & 63;
    const int wr = wave >> 1, wc = wave & 1;
    const int r0 = blockIdx.x * 128 + wr * 64;
    const int c0 = wc * 64;
    const int l15 = lane & 15, lhi = lane >> 4;
    f32x4 acc[4][4] = {};
    #pragma unroll
    for (int kk = 0; kk < 4; ++kk) {
        const int kb = kk * 32 + lhi * 8;
        bf16x8 a[4], b[4];
        #pragma unroll
        for (int m = 0; m < 4; ++m) {
            int row = r0 + m * 16 + l15;
            row = row < M ? row : M - 1;
            const float* ap = A + (size_t)row * 128 + kb;
            float4 v0 = *(const float4*)ap;
            float4 v1 = *(const float4*)(ap + 4);
            bf16x8 f;
            f[0]=(__bf16)v0.x; f[1]=(__bf16)v0.y; f[2]=(__bf16)v0.z; f[3]=(__bf16)v0.w;
            f[4]=(__bf16)v1.x; f[5]=(__bf16)v1.y; f[6]=(__bf16)v1.z; f[7]=(__bf16)v1.w;
            a[m] = f;
        }
        #pragma unroll
        for (int n = 0; n < 4; ++n) {
            int col = c0 + n * 16 + l15;
            b[n] = *(const bf16x8*)(Wt + (size_t)col * 128 + kb);
        }
        #pragma unroll
        for (int m = 0; m < 4; ++m)
            #pragma unroll
            for (int n = 0; n < 4; ++n)
                acc[m][n] = __builtin_amdgcn_mfma_f32_16x16x32_bf16(a[m], b[n], acc[m][n], 0, 0, 0);
    }
    #pragma unroll
    for (int m = 0; m < 4; ++m)
        #pragma unroll
        for (int j = 0; j < 4; ++j) {
            int row = r0 + m * 16 + lhi * 4 + j;
            if (row >= M) continue;
            #pragma unroll
            for (int n = 0; n < 4; ++n) {
                int col = c0 + n * 16 + l15;
                out[(size_t)row * 128 + col] = (__bf16)(acc[m][n][j] + bias[col]);
            }
        }
}

// ---------------- gather + per-basis aggregate, ILP-pipelined ----------------
// one wave per dst node; lane owns channels 2*lane, 2*lane+1.
// perm entries preloaded 64-at-a-time into lane regs, broadcast via shfl;
// 4 independent gathers in flight per iteration.
__global__ void k_agg3(const __bf16* __restrict__ x, const int* __restrict__ perm,
                       const int* __restrict__ rowst, const int* __restrict__ deg,
                       const float* __restrict__ att, __bf16* __restrict__ agg,
                       int nodeOff, int nodeCnt) {
    int local = blockIdx.x * 4 + (threadIdx.x >> 6);
    if (local >= nodeCnt) return;
    int node = nodeOff + local;
    int lane = threadIdx.x & 63;
    int start = rowst[node], cnt = deg[node];
    const unsigned int* xs = (const unsigned int*)x;   // 2 bf16 per u32, row stride 64 u32
    float a0=0,a1=0,a2=0,a3=0,a4=0,a5=0,a6=0,a7=0;
    for (int base = 0; base < cnt; base += 64) {
        int nb = cnt - base; if (nb > 64) nb = 64;
        int pl = (lane < nb) ? perm[start + base + lane] : 0;
        int i = 0;
        for (; i + 4 <= nb; i += 4) {
            int p0 = __shfl(pl, i);
            int p1 = __shfl(pl, i + 1);
            int p2 = __shfl(pl, i + 2);
            int p3 = __shfl(pl, i + 3);
            unsigned int u0 = xs[(size_t)(p0 & 0xFFFF) * 64 + lane];
            unsigned int u1 = xs[(size_t)(p1 & 0xFFFF) * 64 + lane];
            unsigned int u2 = xs[(size_t)(p2 & 0xFFFF) * 64 + lane];
            unsigned int u3 = xs[(size_t)(p3 & 0xFFFF) * 64 + lane];
            float4 c0v = *(const float4*)(att + (p0 >> 16) * 4);
            float4 c1v = *(const float4*)(att + (p1 >> 16) * 4);
            float4 c2v = *(const float4*)(att + (p2 >> 16) * 4);
            float4 c3v = *(const float4*)(att + (p3 >> 16) * 4);
            float xl, xh;
            xl = bf2f(u0); xh = bf2fh(u0);
            a0 += c0v.x*xl; a1 += c0v.x*xh; a2 += c0v.y*xl; a3 += c0v.y*xh;
            a4 += c0v.z*xl; a5 += c0v.z*xh; a6 += c0v.w*xl; a7 += c0v.w*xh;
            xl = bf2f(u1); xh = bf2fh(u1);
            a0 += c1v.x*xl; a1 += c1v.x*xh; a2 += c1v.y*xl; a3 += c1v.y*xh;
            a4 += c1v.z*xl; a5 += c1v.z*xh; a6 += c1v.w*xl; a7 += c1v.w*xh;
            xl = bf2f(u2); xh = bf2fh(u2);
            a0 += c2v.x*xl; a1 += c2v.x*xh; a2 += c2v.y*xl; a3 += c2v.y*xh;
            a4 += c2v.z*xl; a5 += c2v.z*xh; a6 += c2v.w*xl; a7 += c2v.w*xh;
            xl = bf2f(u3); xh = bf2fh(u3);
            a0 += c3v.x*xl; a1 += c3v.x*xh; a2 += c3v.y*xl; a3 += c3v.y*xh;
            a4 += c3v.z*xl; a5 += c3v.z*xh; a6 += c3v.w*xl; a7 += c3v.w*xh;
        }
        for (; i < nb; ++i) {
            int p = __shfl(pl, i);
            unsigned int u = xs[(size_t)(p & 0xFFFF) * 64 + lane];
            float4 cf = *(const float4*)(att + (p >> 16) * 4);
            float xl = bf2f(u), xh = bf2fh(u);
            a0 += cf.x*xl; a1 += cf.x*xh; a2 += cf.y*xl; a3 += cf.y*xh;
            a4 += cf.z*xl; a5 += cf.z*xh; a6 += cf.w*xl; a7 += cf.w*xh;
        }
    }
    float dinv = (cnt > 0) ? 1.f / (float)cnt : 0.f;
    unsigned int* ao = (unsigned int*)(agg + (size_t)local * 512);
    ao[0 * 64 + lane] = packbf2(a0 * dinv, a1 * dinv);
    ao[1 * 64 + lane] = packbf2(a2 * dinv, a3 * dinv);
    ao[2 * 64 + lane] = packbf2(a4 * dinv, a5 * dinv);
    ao[3 * 64 + lane] = packbf2(a6 * dinv, a7 * dinv);
}

// ---------------- layer GEMM: y = [agg | x] @ Wt(128x640)^T + rb ; LN(+ReLU) fused ----------------
template<int OUTF>
__global__ void k_gemm_layer(const __bf16* __restrict__ agg, const __bf16* __restrict__ x,
                             const __bf16* __restrict__ Wt, const float* __restrict__ rb,
                             const float* __restrict__ g, const float* __restrict__ bb,
                             __bf16* __restrict__ outB, float* __restrict__ outF,
                             int rowOff, int nodeCnt) {
    __shared__ float red[2][2][128];
    __shared__ float murs[2][128];
    const int tid = threadIdx.x, wave = tid >> 6, lane = tid & 63;
    const int wr = wave >> 1, wc = wave & 1;
    const int lr0 = blockIdx.x * 128 + wr * 64;
    const int c0 = wc * 64;
    const int l15 = lane & 15, lhi = lane >> 4;
    f32x4 acc[4][4] = {};
    #pragma unroll
    for (int kk = 0; kk < 20; ++kk) {
        const int kb = kk * 32 + lhi * 8;
        bf16x8 a[4], b[4];
        #pragma unroll
        for (int m = 0; m < 4; ++m) {
            int lr = lr0 + m * 16 + l15;
            lr = lr < nodeCnt ? lr : nodeCnt - 1;
            if (kk < 16) a[m] = *(const bf16x8*)(agg + (size_t)lr * 512 + kb);
            else         a[m] = *(const bf16x8*)(x + (size_t)(rowOff + lr) * 128 + (kb - 512));
        }
        #pragma unroll
        for (int n = 0; n < 4; ++n) {
            int col = c0 + n * 16 + l15;
            b[n] = *(const bf16x8*)(Wt + (size_t)col * 640 + kb);
        }
        #pragma unroll
        for (int m = 0; m < 4; ++m)
            #pragma unroll
            for (int n = 0; n < 4; ++n)
                acc[m][n] = __builtin_amdgcn_mfma_f32_16x16x32_bf16(a[m], b[n], acc[m][n], 0, 0, 0);
    }
    float colb[4];
    #pragma unroll
    for (int n = 0; n < 4; ++n) colb[n] = rb[c0 + n * 16 + l15];
    #pragma unroll
    for (int m = 0; m < 4; ++m)
        #pragma unroll
        for (int j = 0; j < 4; ++j) {
            float s = 0.f, q = 0.f;
            #pragma unroll
            for (int n = 0; n < 4; ++n) {
                float v = acc[m][n][j] + colb[n];
                acc[m][n][j] = v;
                s += v; q += v * v;
            }
            #pragma unroll
            for (int o = 1; o < 16; o <<= 1) { s += __shfl_xor(s, o); q += __shfl_xor(q, o); }
            if (l15 == 0) {
                int r = wr * 64 + m * 16 + lhi * 4 + j;
                red[0][wc][r] = s; red[1][wc][r] = q;
            }
        }
    __syncthreads();
    if (tid < 128) {
        float s = red[0][0][tid] + red[0][1][tid];
        float q = red[1][0][tid] + red[1][1][tid];
        float mu = s * (1.f / 128.f);
        float var = q * (1.f / 128.f) - mu * mu;
        murs[0][tid] = mu;
        murs[1][tid] = rsqrtf(var + 1e-5f);
    }
    __syncthreads();
    float gg[4], gb[4];
    #pragma unroll
    for (int n = 0; n < 4; ++n) {
        int col = c0 + n * 16 + l15;
        gg[n] = g[col]; gb[n] = bb[col];
    }
    #pragma unroll
    for (int m = 0; m < 4; ++m)
        #pragma unroll
        for (int j = 0; j < 4; ++j) {
            int rblk = wr * 64 + m * 16 + lhi * 4 + j;
            int lr = blockIdx.x * 128 + rblk;
            if (lr >= nodeCnt) continue;
            float mu = murs[0][rblk], rs = murs[1][rblk];
            size_t rowbase = (size_t)(rowOff + lr) * 128;
            #pragma unroll
            for (int n = 0; n < 4; ++n) {
                int col = c0 + n * 16 + l15;
                float v = (acc[m][n][j] - mu) * rs * gg[n] + gb[n];
                if (OUTF == 0) { v = fmaxf(v, 0.f); outB[rowbase + col] = (__bf16)v; }
                else           { outF[rowbase + col] = v; }
            }
        }
}

// ---------------- launch ----------------
extern "C" void kernel_launch(void* const* d_in, const int* in_sizes, int n_in,
                              void* d_out, int out_size, void* d_ws, size_t ws_size,
                              hipStream_t stream) {
    const float* nf      = (const float*)d_in[0];
    const int*   et      = (const int*)d_in[1];
    const float* input_w = (const float*)d_in[3];
    const float* input_b = (const float*)d_in[4];
    const float* basis0  = (const float*)d_in[5];
    const float* att0    = (const float*)d_in[6];
    const float* rootw0  = (const float*)d_in[7];
    const float* rootb0  = (const float*)d_in[8];
    const float* lng0    = (const float*)d_in[9];
    const float* lnb0    = (const float*)d_in[10];
    const float* basis1  = (const float*)d_in[11];
    const float* att1    = (const float*)d_in[12];
    const float* rootw1  = (const float*)d_in[13];
    const float* rootb1  = (const float*)d_in[14];
    const float* lng1    = (const float*)d_in[15];
    const float* lnb1    = (const float*)d_in[16];
    (void)in_sizes; (void)n_in; (void)out_size;

    char* ws = (char*)d_ws;
    size_t off = 0;
    auto carve = [&](size_t bytes) { char* p = ws + off; off = (off + bytes + 255) & ~(size_t)255; return p; };
    __bf16* x0    = (__bf16*)carve((size_t)NN * 128 * 2);     // 12.8 MB
    __bf16* x1    = (__bf16*)carve((size_t)NN * 128 * 2);     // 12.8 MB
    __bf16* WtIn  = (__bf16*)carve((size_t)128 * 128 * 2);
    __bf16* Wt0   = (__bf16*)carve((size_t)128 * 640 * 2);
    __bf16* Wt1   = (__bf16*)carve((size_t)128 * 640 * 2);
    int*    deg   = (int*)carve((size_t)NN * 4);
    int*    incl  = (int*)carve((size_t)NN * 4);
    int*    rowst = (int*)carve((size_t)NN * 4);
    int*    curs  = (int*)carve((size_t)NN * 4);
    int*    bsum  = (int*)carve(64 * 4);
    int*    boff  = (int*)carve(64 * 4);
    int*    perm  = (int*)carve((size_t)EE * 4);              // 3.2 MB
    size_t remain = (ws_size > off + 4096) ? (ws_size - off - 4096) : 0;
    long long maxNodes = (long long)(remain / 1024);          // 1 KB per node
    int chunkN = (maxNodes >= NN) ? NN : (int)maxNodes;
    if (chunkN < 512) chunkN = 512;
    __bf16* agg = (__bf16*)carve((size_t)chunkN * 512 * 2);
    int nch = (NN + chunkN - 1) / chunkN;

    // CSR build
    k_zero<<<(NN + 255) / 256, 256, 0, stream>>>(deg, curs);
    k_deg<<<(EE + 255) / 256, 256, 0, stream>>>(et, deg);
    k_scan1<<<49, 1024, 0, stream>>>(deg, incl, bsum);
    k_scan2<<<1, 64, 0, stream>>>(bsum, boff);
    k_scan3<<<49, 1024, 0, stream>>>(incl, deg, boff, rowst);
    k_fill<<<(EE + 255) / 256, 256, 0, stream>>>(et, rowst, curs, perm);

    // weights (one dispatch) + input projection
    k_prep<<<(16384 + 2 * 81920 + 255) / 256, 256, 0, stream>>>(input_w, basis0, rootw0,
                                                                basis1, rootw1, WtIn, Wt0, Wt1);
    k_gemm_in<<<(NN + 127) / 128, 256, 0, stream>>>(nf, WtIn, input_b, x0, NN);

    // layer 0
    for (int c = 0; c < nch; ++c) {
        int o0 = c * chunkN;
        int cnt = (o0 + chunkN <= NN) ? chunkN : (NN - o0);
        k_agg3<<<(cnt + 3) / 4, 256, 0, stream>>>(x0, perm, rowst, deg, att0, agg, o0, cnt);
        k_gemm_layer<0><<<(cnt + 127) / 128, 256, 0, stream>>>(agg, x0, Wt0, rootb0, lng0, lnb0,
                                                               x1, nullptr, o0, cnt);
    }

    // layer 1
    for (int c = 0; c < nch; ++c) {
        int o0 = c * chunkN;
        int cnt = (o0 + chunkN <= NN) ? chunkN : (NN - o0);
        k_agg3<<<(cnt + 3) / 4, 256, 0, stream>>>(x1, perm, rowst, deg, att1, agg, o0, cnt);
        k_gemm_layer<1><<<(cnt + 127) / 128, 256, 0, stream>>>(agg, x1, Wt1, rootb1, lng1, lnb1,
                                                               nullptr, (float*)d_out, o0, cnt);
    }
}

// Round 4
// 263.291 us; speedup vs baseline: 1.4509x; 1.0787x over previous
//
#include <hip/hip_runtime.h>
#include <hip/hip_bf16.h>

#define NN 50000
#define EE 800000

typedef __bf16 bf16x8 __attribute__((ext_vector_type(8)));
typedef float f32x4 __attribute__((ext_vector_type(4)));

__device__ inline float bf2f(unsigned int u) {
    union { unsigned int i; float f; } x; x.i = (u & 0xFFFFu) << 16; return x.f;
}
__device__ inline float bf2fh(unsigned int u) {
    union { unsigned int i; float f; } x; x.i = u & 0xFFFF0000u; return x.f;
}
__device__ inline void bf8_to_f(bf16x8 v, float* f) {
    const unsigned int* u = (const unsigned int*)&v;
    f[0] = bf2f(u[0]); f[1] = bf2fh(u[0]);
    f[2] = bf2f(u[1]); f[3] = bf2fh(u[1]);
    f[4] = bf2f(u[2]); f[5] = bf2fh(u[2]);
    f[6] = bf2f(u[3]); f[7] = bf2fh(u[3]);
}

// ---------------- zero deg/cursor (graph-safe) ----------------
__global__ void k_zero(int* __restrict__ deg, int* __restrict__ curs) {
    int i = blockIdx.x * 256 + threadIdx.x;
    if (i < NN) { deg[i] = 0; curs[i] = 0; }
}

// ---------------- CSR build ----------------
__global__ void k_deg(const int* __restrict__ et, int* __restrict__ deg) {
    int e = blockIdx.x * 256 + threadIdx.x;
    if (e < EE) atomicAdd(&deg[et[e * 3 + 2]], 1);
}

__global__ void k_scan1(const int* __restrict__ deg, int* __restrict__ incl, int* __restrict__ bsum) {
    __shared__ int s[1024];
    int i = blockIdx.x * 1024 + threadIdx.x;
    int v = (i < NN) ? deg[i] : 0;
    s[threadIdx.x] = v;
    __syncthreads();
    for (int off = 1; off < 1024; off <<= 1) {
        int t = (threadIdx.x >= off) ? s[threadIdx.x - off] : 0;
        __syncthreads();
        s[threadIdx.x] += t;
        __syncthreads();
    }
    if (i < NN) incl[i] = s[threadIdx.x];
    if (threadIdx.x == 1023) bsum[blockIdx.x] = s[1023];
}

__global__ void k_scan2(const int* __restrict__ bsum, int* __restrict__ boff) {
    if (threadIdx.x == 0 && blockIdx.x == 0) {
        int acc = 0;
        for (int i = 0; i < 49; ++i) { boff[i] = acc; acc += bsum[i]; }
    }
}

__global__ void k_scan3(const int* __restrict__ incl, const int* __restrict__ deg,
                        const int* __restrict__ boff, int* __restrict__ row_start) {
    int i = blockIdx.x * 1024 + threadIdx.x;
    if (i < NN) row_start[i] = incl[i] - deg[i] + boff[blockIdx.x];
}

__global__ void k_fill(const int* __restrict__ et, const int* __restrict__ row_start,
                       int* __restrict__ cursor, int* __restrict__ perm) {
    int e = blockIdx.x * 256 + threadIdx.x;
    if (e >= EE) return;
    int src = et[e * 3 + 0];
    int rel = et[e * 3 + 1];
    int dst = et[e * 3 + 2];
    int pos = row_start[dst] + atomicAdd(&cursor[dst], 1);
    perm[pos] = src | (rel << 16);      // src < 65536, rel < 16
}

// ---------------- fragment-major weight prep ----------------
// WtInF: chunks ((nblk*4+kk)*64+lane)*8, nblk=col/16 (8), kk=k/32 (4)
//   lane=(lhi*16+l15): col=nblk*16+l15, k=kk*32+lhi*8+j, src iw[k*128+col]
// WtF{0,1}: ((nblk*20+kk)*64+lane)*8, kk 0..19; k<512->basis[k>>7][k&127][col], else rootw[k-512][col]
__global__ void k_prep(const float* __restrict__ iw,
                       const float* __restrict__ basis0, const float* __restrict__ rootw0,
                       const float* __restrict__ basis1, const float* __restrict__ rootw1,
                       __bf16* __restrict__ WtInF, __bf16* __restrict__ WtF0, __bf16* __restrict__ WtF1) {
    int t = blockIdx.x * 256 + threadIdx.x;
    if (t < 2048) {
        int lane = t & 63, grp = t >> 6;       // grp = nblk*4+kk
        int kk = grp & 3, nblk = grp >> 2;
        int col = nblk * 16 + (lane & 15);
        int k0 = kk * 32 + (lane >> 4) * 8;
        bf16x8 v;
        #pragma unroll
        for (int j = 0; j < 8; ++j) v[j] = (__bf16)iw[(size_t)(k0 + j) * 128 + col];
        *(bf16x8*)(WtInF + (size_t)t * 8) = v;
        return;
    }
    t -= 2048;
    const float* basis = basis0; const float* rootw = rootw0; __bf16* W = WtF0;
    if (t >= 10240) { t -= 10240; basis = basis1; rootw = rootw1; W = WtF1; }
    if (t >= 10240) return;
    int lane = t & 63, grp = t >> 6;           // grp = nblk*20+kk
    int kk = grp % 20, nblk = grp / 20;
    int col = nblk * 16 + (lane & 15);
    int k0 = kk * 32 + (lane >> 4) * 8;
    bf16x8 v;
    #pragma unroll
    for (int j = 0; j < 8; ++j) {
        int k = k0 + j;
        float f = (k < 512) ? basis[(size_t)(k >> 7) * 16384 + (size_t)(k & 127) * 128 + col]
                            : rootw[(size_t)(k - 512) * 128 + col];
        v[j] = (__bf16)f;
    }
    *(bf16x8*)(W + (size_t)t * 8) = v;
}

// ---------------- input GEMM: x0 = nf(f32) @ input_w + b (bf16 out), 64-row tiles ----------------
__global__ void k_gemm_in(const float* __restrict__ A, const __bf16* __restrict__ WtInF,
                          const float* __restrict__ bias, __bf16* __restrict__ out, int M) {
    const int tid = threadIdx.x, wave = tid >> 6, lane = tid & 63;
    const int wr = wave >> 1, wc = wave & 1;
    const int l15 = lane & 15, lhi = lane >> 4;
    f32x4 acc[2][4] = {};
    #define LDAI(dst, KK) do { \
        _Pragma("unroll") \
        for (int m = 0; m < 2; ++m) { \
            int rw = blockIdx.x * 64 + wr * 32 + m * 16 + l15; \
            rw = rw < M ? rw : M - 1; \
            const float* ap = A + (size_t)rw * 128 + (KK) * 32 + lhi * 8; \
            float4 v0 = *(const float4*)ap, v1 = *(const float4*)(ap + 4); \
            bf16x8 f; \
            f[0]=(__bf16)v0.x; f[1]=(__bf16)v0.y; f[2]=(__bf16)v0.z; f[3]=(__bf16)v0.w; \
            f[4]=(__bf16)v1.x; f[5]=(__bf16)v1.y; f[6]=(__bf16)v1.z; f[7]=(__bf16)v1.w; \
            dst[m] = f; \
        } } while (0)
    #define LDBI(dst, KK) do { \
        _Pragma("unroll") \
        for (int n = 0; n < 4; ++n) \
            dst[n] = *(const bf16x8*)(WtInF + (((size_t)(wc * 4 + n) * 4 + (KK)) * 64 + lane) * 8); \
        } while (0)
    #define MMI(AA, BB) do { \
        _Pragma("unroll") for (int m = 0; m < 2; ++m) \
        _Pragma("unroll") for (int n = 0; n < 4; ++n) \
            acc[m][n] = __builtin_amdgcn_mfma_f32_16x16x32_bf16(AA[m], BB[n], acc[m][n], 0, 0, 0); \
        } while (0)
    bf16x8 aP[2], bP[4], aQ[2], bQ[4];
    LDAI(aP, 0); LDBI(bP, 0);
    #pragma unroll
    for (int tstep = 0; tstep < 2; ++tstep) {
        LDAI(aQ, 2 * tstep + 1); LDBI(bQ, 2 * tstep + 1);
        MMI(aP, bP);
        if (tstep < 1) { LDAI(aP, 2 * tstep + 2); LDBI(bP, 2 * tstep + 2); }
        MMI(aQ, bQ);
    }
    #pragma unroll
    for (int m = 0; m < 2; ++m)
        #pragma unroll
        for (int j = 0; j < 4; ++j) {
            int row = blockIdx.x * 64 + wr * 32 + m * 16 + lhi * 4 + j;
            if (row >= M) continue;
            #pragma unroll
            for (int n = 0; n < 4; ++n) {
                int col = wc * 64 + n * 16 + l15;
                out[(size_t)row * 128 + col] = (__bf16)(acc[m][n][j] + bias[col]);
            }
        }
}

// ---------------- gather + aggregate, fragment-major output ----------------
// 16 lanes per edge (lane owns 8 consecutive channels), 4 edges per load, 8 in flight.
// Output aggF in MFMA fragment order: bf16 idx = ((grp16*16 + b*4 + c8/4)*64 + (c8&3)*16 + (local&15))*8
__global__ void k_agg4(const __bf16* __restrict__ x, const int* __restrict__ perm,
                       const int* __restrict__ rowst, const int* __restrict__ deg,
                       const float* __restrict__ att, __bf16* __restrict__ aggF,
                       int nodeOff, int nodeCnt) {
    __shared__ float4 satt[16];
    if (threadIdx.x < 16) satt[threadIdx.x] = ((const float4*)att)[threadIdx.x];
    __syncthreads();
    int local = blockIdx.x * 4 + (threadIdx.x >> 6);
    if (local >= nodeCnt) return;
    int lane = threadIdx.x & 63;
    int e4 = lane >> 4, c8 = lane & 15;
    int node = nodeOff + local;
    int start = rowst[node], cnt = deg[node];
    float acc[4][8] = {};
    int nIt = (cnt + 3) >> 2;
    for (int it = 0; it < nIt; it += 2) {
        int eA = it * 4 + e4, eB = eA + 4;
        bool vA = eA < cnt, vB = eB < cnt;
        int pA = vA ? perm[start + eA] : 0;
        int pB = vB ? perm[start + eB] : 0;
        bf16x8 uA = *(const bf16x8*)(x + (size_t)(pA & 0xFFFF) * 128 + c8 * 8);
        bf16x8 uB = *(const bf16x8*)(x + (size_t)(pB & 0xFFFF) * 128 + c8 * 8);
        float4 cA = satt[pA >> 16];
        float4 cB = satt[pB >> 16];
        if (!vA) cA = make_float4(0.f, 0.f, 0.f, 0.f);
        if (!vB) cB = make_float4(0.f, 0.f, 0.f, 0.f);
        float fA[8], fB[8];
        bf8_to_f(uA, fA);
        bf8_to_f(uB, fB);
        #pragma unroll
        for (int j = 0; j < 8; ++j) {
            acc[0][j] += cA.x * fA[j]; acc[1][j] += cA.y * fA[j];
            acc[2][j] += cA.z * fA[j]; acc[3][j] += cA.w * fA[j];
        }
        #pragma unroll
        for (int j = 0; j < 8; ++j) {
            acc[0][j] += cB.x * fB[j]; acc[1][j] += cB.y * fB[j];
            acc[2][j] += cB.z * fB[j]; acc[3][j] += cB.w * fB[j];
        }
    }
    float dinv = (cnt > 0) ? 1.f / (float)cnt : 0.f;
    #pragma unroll
    for (int b = 0; b < 4; ++b)
        #pragma unroll
        for (int j = 0; j < 8; ++j) {
            float v = acc[b][j];
            v += __shfl_xor(v, 16);
            v += __shfl_xor(v, 32);
            acc[b][j] = v * dinv;
        }
    bf16x8 o;
    #pragma unroll
    for (int j = 0; j < 8; ++j) {
        float v = (e4 == 0) ? acc[0][j] : (e4 == 1) ? acc[1][j] : (e4 == 2) ? acc[2][j] : acc[3][j];
        o[j] = (__bf16)v;
    }
    size_t idx8 = (((size_t)(local >> 4) * 16 + e4 * 4 + (c8 >> 2)) * 64 + (c8 & 3) * 16 + (local & 15)) * 8;
    *(bf16x8*)(aggF + idx8) = o;
}

// ---------------- layer GEMM: y = [agg | x] @ W + rb ; LN(+ReLU) fused; 64-row tiles ----------------
template<int OUTF>
__global__ void k_gemm_layer(const __bf16* __restrict__ aggF, const __bf16* __restrict__ x,
                             const __bf16* __restrict__ WtF, const float* __restrict__ rb,
                             const float* __restrict__ g, const float* __restrict__ bb,
                             __bf16* __restrict__ outB, float* __restrict__ outF,
                             int rowOff, int nodeCnt) {
    __shared__ float red[2][2][64];
    __shared__ float murs[2][64];
    const int tid = threadIdx.x, wave = tid >> 6, lane = tid & 63;
    const int wr = wave >> 1, wc = wave & 1;
    const int l15 = lane & 15, lhi = lane >> 4;
    const int rowgrpBase = blockIdx.x * 4 + wr * 2;   // 16-node groups
    f32x4 acc[2][4] = {};
    #define LDA(dst, KK) do { \
        _Pragma("unroll") \
        for (int m = 0; m < 2; ++m) { \
            if ((KK) < 16) { \
                dst[m] = *(const bf16x8*)(aggF + (((size_t)(rowgrpBase + m) * 16 + (KK)) * 64 + lane) * 8); \
            } else { \
                int rw = blockIdx.x * 64 + wr * 32 + m * 16 + l15; \
                rw = rw < nodeCnt ? rw : nodeCnt - 1; \
                dst[m] = *(const bf16x8*)(x + (size_t)(rowOff + rw) * 128 + ((KK) - 16) * 32 + lhi * 8); \
            } \
        } } while (0)
    #define LDB(dst, KK) do { \
        _Pragma("unroll") \
        for (int n = 0; n < 4; ++n) \
            dst[n] = *(const bf16x8*)(WtF + (((size_t)(wc * 4 + n) * 20 + (KK)) * 64 + lane) * 8); \
        } while (0)
    #define MM(AA, BB) do { \
        _Pragma("unroll") for (int m = 0; m < 2; ++m) \
        _Pragma("unroll") for (int n = 0; n < 4; ++n) \
            acc[m][n] = __builtin_amdgcn_mfma_f32_16x16x32_bf16(AA[m], BB[n], acc[m][n], 0, 0, 0); \
        } while (0)
    bf16x8 aP[2], bP[4], aQ[2], bQ[4];
    LDA(aP, 0); LDB(bP, 0);
    #pragma unroll
    for (int t = 0; t < 10; ++t) {
        LDA(aQ, 2 * t + 1); LDB(bQ, 2 * t + 1);
        MM(aP, bP);
        if (t < 9) { LDA(aP, 2 * t + 2); LDB(bP, 2 * t + 2); }
        MM(aQ, bQ);
    }
    // + root bias, per-row sum/sumsq (16-lane butterfly), LN
    float colb[4];
    #pragma unroll
    for (int n = 0; n < 4; ++n) colb[n] = rb[wc * 64 + n * 16 + l15];
    #pragma unroll
    for (int m = 0; m < 2; ++m)
        #pragma unroll
        for (int j = 0; j < 4; ++j) {
            float s = 0.f, q = 0.f;
            #pragma unroll
            for (int n = 0; n < 4; ++n) {
                float v = acc[m][n][j] + colb[n];
                acc[m][n][j] = v;
                s += v; q += v * v;
            }
            #pragma unroll
            for (int o = 1; o < 16; o <<= 1) { s += __shfl_xor(s, o); q += __shfl_xor(q, o); }
            if (l15 == 0) {
                int r = wr * 32 + m * 16 + lhi * 4 + j;
                red[0][wc][r] = s; red[1][wc][r] = q;
            }
        }
    __syncthreads();
    if (tid < 64) {
        float s = red[0][0][tid] + red[0][1][tid];
        float q = red[1][0][tid] + red[1][1][tid];
        float mu = s * (1.f / 128.f);
        float var = q * (1.f / 128.f) - mu * mu;
        murs[0][tid] = mu;
        murs[1][tid] = rsqrtf(var + 1e-5f);
    }
    __syncthreads();
    float gg[4], gb[4];
    #pragma unroll
    for (int n = 0; n < 4; ++n) {
        int col = wc * 64 + n * 16 + l15;
        gg[n] = g[col]; gb[n] = bb[col];
    }
    #pragma unroll
    for (int m = 0; m < 2; ++m)
        #pragma unroll
        for (int j = 0; j < 4; ++j) {
            int rblk = wr * 32 + m * 16 + lhi * 4 + j;
            int lr = blockIdx.x * 64 + rblk;
            if (lr >= nodeCnt) continue;
            float mu = murs[0][rblk], rs = murs[1][rblk];
            size_t rowbase = (size_t)(rowOff + lr) * 128;
            #pragma unroll
            for (int n = 0; n < 4; ++n) {
                int col = wc * 64 + n * 16 + l15;
                float v = (acc[m][n][j] - mu) * rs * gg[n] + gb[n];
                if (OUTF == 0) { v = fmaxf(v, 0.f); outB[rowbase + col] = (__bf16)v; }
                else           { outF[rowbase + col] = v; }
            }
        }
}

// ---------------- launch ----------------
extern "C" void kernel_launch(void* const* d_in, const int* in_sizes, int n_in,
                              void* d_out, int out_size, void* d_ws, size_t ws_size,
                              hipStream_t stream) {
    const float* nf      = (const float*)d_in[0];
    const int*   et      = (const int*)d_in[1];
    const float* input_w = (const float*)d_in[3];
    const float* input_b = (const float*)d_in[4];
    const float* basis0  = (const float*)d_in[5];
    const float* att0    = (const float*)d_in[6];
    const float* rootw0  = (const float*)d_in[7];
    const float* rootb0  = (const float*)d_in[8];
    const float* lng0    = (const float*)d_in[9];
    const float* lnb0    = (const float*)d_in[10];
    const float* basis1  = (const float*)d_in[11];
    const float* att1    = (const float*)d_in[12];
    const float* rootw1  = (const float*)d_in[13];
    const float* rootb1  = (const float*)d_in[14];
    const float* lng1    = (const float*)d_in[15];
    const float* lnb1    = (const float*)d_in[16];
    (void)in_sizes; (void)n_in; (void)out_size;

    char* ws = (char*)d_ws;
    size_t off = 0;
    auto carve = [&](size_t bytes) { char* p = ws + off; off = (off + bytes + 255) & ~(size_t)255; return p; };
    __bf16* x0    = (__bf16*)carve((size_t)NN * 128 * 2);     // 12.8 MB
    __bf16* x1    = (__bf16*)carve((size_t)NN * 128 * 2);     // 12.8 MB
    __bf16* WtInF = (__bf16*)carve((size_t)128 * 128 * 2);
    __bf16* WtF0  = (__bf16*)carve((size_t)128 * 640 * 2);
    __bf16* WtF1  = (__bf16*)carve((size_t)128 * 640 * 2);
    int*    deg   = (int*)carve((size_t)NN * 4);
    int*    incl  = (int*)carve((size_t)NN * 4);
    int*    rowst = (int*)carve((size_t)NN * 4);
    int*    curs  = (int*)carve((size_t)NN * 4);
    int*    bsum  = (int*)carve(64 * 4);
    int*    boff  = (int*)carve(64 * 4);
    int*    perm  = (int*)carve((size_t)EE * 4 + 64);         // +pad for tail reads
    size_t remain = (ws_size > off + 4096) ? (ws_size - off - 4096) : 0;
    long long maxNodes = (long long)(remain / 1024);          // 1 KB per node
    int chunkN = (maxNodes >= NN) ? NN : (int)maxNodes;
    if (chunkN < 512) chunkN = 512;
    chunkN = (chunkN + 63) & ~63;                             // 64-node groups
    __bf16* aggF = (__bf16*)carve((size_t)chunkN * 512 * 2);
    int nch = (NN + chunkN - 1) / chunkN;

    // CSR build
    k_zero<<<(NN + 255) / 256, 256, 0, stream>>>(deg, curs);
    k_deg<<<(EE + 255) / 256, 256, 0, stream>>>(et, deg);
    k_scan1<<<49, 1024, 0, stream>>>(deg, incl, bsum);
    k_scan2<<<1, 64, 0, stream>>>(bsum, boff);
    k_scan3<<<49, 1024, 0, stream>>>(incl, deg, boff, rowst);
    k_fill<<<(EE + 255) / 256, 256, 0, stream>>>(et, rowst, curs, perm);

    // weights + input projection
    k_prep<<<88, 256, 0, stream>>>(input_w, basis0, rootw0, basis1, rootw1, WtInF, WtF0, WtF1);
    k_gemm_in<<<(NN + 63) / 64, 256, 0, stream>>>(nf, WtInF, input_b, x0, NN);

    // layer 0
    for (int c = 0; c < nch; ++c) {
        int o0 = c * chunkN;
        int cnt = (o0 + chunkN <= NN) ? chunkN : (NN - o0);
        k_agg4<<<(cnt + 3) / 4, 256, 0, stream>>>(x0, perm, rowst, deg, att0, aggF, o0, cnt);
        k_gemm_layer<0><<<(cnt + 63) / 64, 256, 0, stream>>>(aggF, x0, WtF0, rootb0, lng0, lnb0,
                                                             x1, nullptr, o0, cnt);
    }

    // layer 1
    for (int c = 0; c < nch; ++c) {
        int o0 = c * chunkN;
        int cnt = (o0 + chunkN <= NN) ? chunkN : (NN - o0);
        k_agg4<<<(cnt + 3) / 4, 256, 0, stream>>>(x1, perm, rowst, deg, att1, aggF, o0, cnt);
        k_gemm_layer<1><<<(cnt + 63) / 64, 256, 0, stream>>>(aggF, x1, WtF1, rootb1, lng1, lnb1,
                                                             nullptr, (float*)d_out, o0, cnt);
    }
}